// Round 6
// baseline (357.051 us; speedup 1.0000x reference)
//
#include <hip/hip_runtime.h>
#include <hip/hip_bf16.h>

#define NG 64       // NUM_GROUPS
#define TOPK 8
#define BM 128      // BLOCK_M
#define NSLOT 65536 // NUM_TOKENS * TOPK
#define HID 4096
#define NTOK 8192

// ws ints: [0..63] counts, [64..127] lastslot(-1), [128..191] padded,
// [192..255] out_start, [256] total. rank u16 at ws+512 (128 KB).

__global__ __launch_bounds__(64) void init_k(int* ws) {
    int t = threadIdx.x;
    if (t < NG) { ws[t] = 0; ws[NG + t] = -1; }
}

__global__ void hist_k(const int* __restrict__ ids, int* __restrict__ ws) {
    __shared__ int h[NG];
    __shared__ int lm[NG];
    int t = threadIdx.x;
    if (t < NG) { h[t] = 0; lm[t] = -1; }
    __syncthreads();
    for (int i = blockIdx.x * blockDim.x + t; i < NSLOT; i += gridDim.x * blockDim.x) {
        int e = ids[i] & (NG - 1);
        atomicAdd(&h[e], 1);
        atomicMax(&lm[e], i);
    }
    __syncthreads();
    if (t < NG) {
        if (h[t]) atomicAdd(&ws[t], h[t]);
        atomicMax(&ws[NG + t], lm[t]);
    }
}

__global__ void scan_k(int* ws) {
    if (threadIdx.x == 0) {
        int acc = 0;
        for (int e = 0; e < NG; e++) {
            int c = ws[e];
            int p = (c + BM - 1) / BM * BM;
            ws[2 * NG + e] = p;
            ws[3 * NG + e] = acc;
            acc += p;
        }
        ws[256] = acc;  // total (== reference's sum of padded)
    }
}

// One wave per expert: stable rank via ballot prefix; also fills m_indices (f32).
__global__ __launch_bounds__(64) void rank_k(const int* __restrict__ ids,
                                             const int* __restrict__ ws,
                                             unsigned short* __restrict__ rank,
                                             float* __restrict__ out) {
    int e = blockIdx.x;
    int lane = threadIdx.x;
    int c = ws[e];
    int p = ws[2 * NG + e];
    int o = ws[3 * NG + e];
    int total = ws[256];

    if (c > 0) {
        int base_r = 0;
        for (int chunk = 0; chunk < NSLOT; chunk += 512) {
            int id[8];
#pragma unroll
            for (int u = 0; u < 8; u++) id[u] = ids[chunk + u * 64 + lane];
#pragma unroll
            for (int u = 0; u < 8; u++) {
                unsigned long long m = __ballot(id[u] == e);
                if (id[u] == e)
                    rank[chunk + u * 64 + lane] =
                        (unsigned short)(base_r + __popcll(m & ((1ULL << lane) - 1ULL)));
                base_r += __popcll(m);
            }
        }
    }
    float* m_out = out + (size_t)total * HID;   // chunk 1 (m_indices, f32)
    float fe = (float)e;
    for (int t2 = lane; t2 < p; t2 += 64) {
        int idx = o + t2;
        if (idx >= 0 && idx < total) m_out[idx] = fe;
    }
}

// inv_perm[v + sum_{f: last_f < v} pad_f] = pos(v); pad entries follow each last slot.
__global__ void inv_k(const int* __restrict__ ids,
                      const int* __restrict__ ws,
                      const unsigned short* __restrict__ rank,
                      float* __restrict__ out) {
    __shared__ int s_last[NG], s_pad[NG];
    int t = threadIdx.x;
    if (t < NG) {
        s_last[t] = ws[NG + t];
        s_pad[t] = ws[2 * NG + t] - ws[t];
    }
    __syncthreads();
    int total = ws[256];
    float* inv_out = out + (size_t)total * (HID + 1);  // chunk 2 (inv_perm, f32)
    int i = blockIdx.x * blockDim.x + t;
    if (i >= NSLOT) return;
    int e = ids[i] & (NG - 1);
    int pos = ws[3 * NG + e] + (int)rank[i];
    int base = i;
#pragma unroll
    for (int f = 0; f < NG; f++) {
        int l = s_last[f];
        base += (l >= 0 && l < i) ? s_pad[f] : 0;
    }
    if (base >= 0 && base < NSLOT) inv_out[base] = (float)pos;
    if (i == s_last[e]) {
        int oc = ws[3 * NG + e] + ws[e];
        int pd = s_pad[e];
        for (int j = 0; j < pd; j++) {
            int idx = base + 1 + j;
            if (idx < 0 || idx >= NSLOT) break;
            inv_out[idx] = (float)(oc + j);
        }
    }
}

// Scatter copy with bf16 -> f32 conversion (f32 bits = u16 << 16).
// Block b < NSLOT: real slot b -> row o_e + rank[b].
// Blocks [NSLOT, NSLOT + NG*BM): pad rows, e=(b-NSLOT)>>7, j=(b-NSLOT)&127.
__global__ __launch_bounds__(256) void copy_k(const __hip_bfloat16* __restrict__ hs,
                                              const int* __restrict__ ids,
                                              const int* __restrict__ ws,
                                              const unsigned short* __restrict__ rank,
                                              float* __restrict__ out) {
    int b = blockIdx.x;
    int total = ws[256];
    int srcslot, dst;
    if (b < NSLOT) {
        int e = ids[b] & (NG - 1);
        srcslot = b;
        dst = ws[3 * NG + e] + (int)rank[b];
    } else {
        int q = b - NSLOT;
        int e = q >> 7;
        int j = q & 127;
        int c = ws[e];
        int p = ws[2 * NG + e];
        if (c + j >= p) return;
        srcslot = ws[NG + e];  // last slot (c>0 guaranteed when pads exist)
        dst = ws[3 * NG + e] + c + j;
    }
    if (dst < 0 || dst >= total) return;
    int src = srcslot / TOPK;
    if (src < 0 || src >= NTOK) return;
    const uint4* s = (const uint4*)(hs + (size_t)src * HID);
    uint4* d = (uint4*)(out + (size_t)dst * HID);
    int t = threadIdx.x;
#pragma unroll
    for (int half = 0; half < 2; half++) {
        int v = half * 256 + t;          // uint4 index into source row (8 bf16 each)
        uint4 w = s[v];
        uint4 o1, o2;
        o1.x = w.x << 16; o1.y = w.x & 0xFFFF0000u;
        o1.z = w.y << 16; o1.w = w.y & 0xFFFF0000u;
        o2.x = w.z << 16; o2.y = w.z & 0xFFFF0000u;
        o2.z = w.w << 16; o2.w = w.w & 0xFFFF0000u;
        d[2 * v] = o1;
        d[2 * v + 1] = o2;
    }
}

extern "C" void kernel_launch(void* const* d_in, const int* in_sizes, int n_in,
                              void* d_out, int out_size, void* d_ws, size_t ws_size,
                              hipStream_t stream) {
    const __hip_bfloat16* hs = (const __hip_bfloat16*)d_in[0];
    const int* ids = (const int*)d_in[1];
    float* out = (float*)d_out;  // mixed-dtype tuple => harness uses float32

    int* ws = (int*)d_ws;
    unsigned short* rank = (unsigned short*)(ws + 512);

    hipLaunchKernelGGL(init_k, dim3(1), dim3(64), 0, stream, ws);
    hipLaunchKernelGGL(hist_k, dim3(64), dim3(256), 0, stream, ids, ws);
    hipLaunchKernelGGL(scan_k, dim3(1), dim3(64), 0, stream, ws);
    hipLaunchKernelGGL(rank_k, dim3(NG), dim3(64), 0, stream, ids, ws, rank, out);
    hipLaunchKernelGGL(inv_k, dim3(NSLOT / 256), dim3(256), 0, stream, ids, ws, rank, out);
    hipLaunchKernelGGL(copy_k, dim3(NSLOT + NG * BM), dim3(256), 0, stream,
                       hs, ids, ws, rank, out);
}